// Round 8
// baseline (139.874 us; speedup 1.0000x reference)
//
#include <hip/hip_runtime.h>
#include <math.h>

// StripePolynomial2d: out[b,c,px,py] = sum_i lut_i(xs_i), where
//   xs_i = 0.5*x + Ax[i]*px + Ay[i]*py + C0[i]   (folded position map)
//   s = floor(xs); d = fract(xs); P = a0 + d*(a1 + d*a2)
// a0=w0/8 (f32), a1,a2 f16 pair. Positions 0,1 merged (theta=0) -> 7 tables.
//
// R8: guard-extended LUT over s in [-4, 515] (520 entries/table): guard
// entries hold the re-centered extrapolation quadratic of segment 0 / 511
// (exact — quadratics closed under shift), reproducing the reference's
// clamped-sid semantics with NO clamp/med3/sub in the hot chain:
//   s = cvt_flr(xs), d = v_fract(xs), ds offset imm absorbs table base.
//
// Structure (R7, verified): 1024 blocks x 512 thr = exactly 4 blocks/CU,
// one round. Wave = one 16x16 patch per k (conflict-free ds_read_b64,
// SQ_LDS_BANK_CONFLICT == 0 measured). Channel-major patch order: LUT
// staged once per block (2/1024 re-stage). No in-loop barriers; rolling
// 1-deep prefetch of next patch's x.

#define WDIM 512
#define HDIM 512
#define SEGS 512
#define NPOS 8
#define NTAB 7
#define NW   1025
#define CCH  3

#define GUARD   4
#define TABLEN  (SEGS + 2 * GUARD)   // 520
#define THREADS 512
#define BLOCKS  1024
#define PER_BLK 48
#define KITER   (PER_BLK / 8)        // 6
#define PATCH_PER_CH 16384           // 16 slices * 1024 patches

struct Params {
    float ax[NPOS];
    float ay[NPOS];
    float c0[NPOS];
};

union HalfPack {
    unsigned int u;
    _Float16 h[2];
};

__global__ __launch_bounds__(THREADS, 8)
void stripe_poly_kernel(const float* __restrict__ x,
                        const float* __restrict__ w,
                        float* __restrict__ out,
                        Params P)
{
    __shared__ uint2 lut[NTAB * TABLEN];   // 29120 B -> 4 blocks/CU

    const int tid  = threadIdx.x;
    const int wv   = tid >> 6;
    const int lane = tid & 63;
    const int plx  = lane >> 2;        // 0..15
    const int ply  = (lane & 3) * 4;   // 0,4,8,12

    const int qbase = blockIdx.x * PER_BLK;

    // ---- LUT staging (channel ch); guard entries re-center seg 0/511 ----
    auto stage = [&](int ch) {
        #pragma unroll
        for (int m = 0; m < NTAB; ++m) {
            for (int e = tid; e < TABLEN; e += THREADS) {
                const int sg = e - GUARD;                       // -4..515
                const int b  = sg < 0 ? 0 : (sg > SEGS - 1 ? SEGS - 1 : sg);
                const float o = (float)(sg - b);                // shift, 0 in-range
                float w0, w1, w2;
                if (m == 0) {
                    const float* wa = w + (size_t)(0 * CCH + ch) * NW + 2 * b;
                    const float* wb = w + (size_t)(1 * CCH + ch) * NW + 2 * b;
                    w0 = wa[0] + wb[0]; w1 = wa[1] + wb[1]; w2 = wa[2] + wb[2];
                } else {
                    const float* wp = w + (size_t)((m + 1) * CCH + ch) * NW + 2 * b;
                    w0 = wp[0]; w1 = wp[1]; w2 = wp[2];
                }
                const float a0 = 0.125f * w0;
                const float a1 = 0.125f * (fmaf(4.0f, w1, -w2) - 3.0f * w0);
                const float a2 = 0.25f  * (w0 - 2.0f * w1 + w2);
                // re-center by o: Q(d) = P(d + o)
                const float q0 = fmaf(o, fmaf(o, a2, a1), a0);
                const float q1 = fmaf(2.0f * o, a2, a1);
                HalfPack hp;
                hp.h[0] = (_Float16)q1;
                hp.h[1] = (_Float16)a2;
                lut[m * TABLEN + e] = make_uint2(__float_as_uint(q0), hp.u);
            }
        }
    };

    // Patch coords for this wave at step k (q is wave-uniform).
    auto coords = [&](int k, int& ch, float& xf, float& yf, size_t& off) {
        const int q   = qbase + k * 8 + wv;
        ch            = q >> 14;
        const int r   = q & (PATCH_PER_CH - 1);
        const int bsl = r >> 10;
        const int pis = r & 1023;
        const int px  = ((pis >> 5) << 4) + plx;
        const int py  = ((pis & 31) << 4) + ply;
        xf = (float)px; yf = (float)py;
        off = ((size_t)(bsl * CCH + ch) << 18) + ((size_t)px << 9) + py;
    };

    int c_cur = qbase >> 14;
    stage(c_cur);

    int ch0; float xf, yf; size_t off;
    coords(0, ch0, xf, yf, off);
    float4 xin = *(const float4*)(x + off);   // overlaps staging
    __syncthreads();

    for (int k = 0; k < KITER; ++k) {
        int chn = 0; float xfn = 0.f, yfn = 0.f; size_t offn = 0;
        float4 xnext;
        if (k + 1 < KITER) {
            coords(k + 1, chn, xfn, yfn, offn);
            xnext = *(const float4*)(x + offn);
        }

        if (ch0 != c_cur) {            // block-uniform; 2/1024 blocks, once
            __syncthreads();
            stage(ch0);
            c_cur = ch0;
            __syncthreads();
        }

        const float xv[4] = {xin.x, xin.y, xin.z, xin.w};
        float acc[4]  = {0.f, 0.f, 0.f, 0.f};
        float accC[4] = {0.f, 0.f, 0.f, 0.f};

        #pragma unroll
        for (int i = 0; i < NTAB; ++i) {
            const int pi = (i == 0) ? 0 : (i + 1);
            const float ay = P.ay[pi];
            const float g  = fmaf(P.ax[pi], xf, fmaf(ay, yf, P.c0[pi]));
            float gj[4];
            gj[0] = g;
            gj[1] = g + ay;
            gj[2] = gj[1] + ay;
            gj[3] = gj[2] + ay;
            const uint2* lt = &lut[i * TABLEN + GUARD];   // imm-folded base
            #pragma unroll
            for (int j = 0; j < 4; ++j) {
                const float xs = fmaf(0.5f, xv[j], gj[j]);
                const int s   = (int)floorf(xs);              // v_cvt_flr_i32_f32
                const float d = __builtin_amdgcn_fractf(xs);  // v_fract_f32
                const uint2 v = lt[s];                        // ds_read_b64
                HalfPack hp; hp.u = v.y;
                const float u = fmaf(d, (float)hp.h[1], (float)hp.h[0]); // v_fma_mix
                accC[j] += __uint_as_float(v.x);
                acc[j]   = fmaf(d, u, acc[j]);
            }
        }

        float4 o;
        o.x = acc[0] + accC[0];
        o.y = acc[1] + accC[1];
        o.z = acc[2] + accC[2];
        o.w = acc[3] + accC[3];
        *(float4*)(out + off) = o;

        xin = xnext; ch0 = chn; xf = xfn; yf = yfn; off = offn;
    }
}

extern "C" void kernel_launch(void* const* d_in, const int* in_sizes, int n_in,
                              void* d_out, int out_size, void* d_ws, size_t ws_size,
                              hipStream_t stream)
{
    const float* x = (const float*)d_in[0];   // [16,3,512,512] f32
    const float* w = (const float*)d_in[1];   // [8,3,1025] f32
    float* out = (float*)d_out;

    // Host-side fold of make_positions() + position_encode + xs rescale.
    // r(x,y) = f32(cx)*x + f32(sgn*cy)*y ; extremes at grid corners (monotone).
    // xs = 0.5*xval + K*(r - rmin), K = 512*RATIO/dr  =>  Ax=K*a, Ay=K*b, C0=-K*rmin.
    Params P;
    const double ratio_f = (double)(float)(512.0 / 513.0);  // numpy casts RATIO to f32
    for (int i = 0; i < 4; ++i) {
        const double theta = (M_PI * 0.5) * ((double)i / 4.0);
        const float a   = (float)cos(theta);
        const float cyf = (float)sin(theta);
        for (int sg = 0; sg < 2; ++sg) {
            const float b = (sg == 0) ? cyf : -cyf;   // f32(sgn*cy)
            const float ax511 = a * 511.0f;
            const float by511 = b * 511.0f;
            float rmin, rmax;
            if (sg == 0) { rmin = 0.0f;  rmax = ax511 + by511; }
            else         { rmin = by511; rmax = ax511; }
            const float dr = rmax - rmin;
            const double K = 512.0 * ratio_f / (double)dr;
            const int pi = 2 * i + sg;
            P.ax[pi] = (float)(K * (double)a);
            P.ay[pi] = (float)(K * (double)b);
            P.c0[pi] = (float)(-K * (double)rmin);
        }
    }

    stripe_poly_kernel<<<BLOCKS, THREADS, 0, stream>>>(x, w, out, P);
}